// Round 7
// baseline (433.995 us; speedup 1.0000x reference)
//
#include <hip/hip_runtime.h>
#include <hip/hip_bf16.h>
#include <math.h>

// Problem constants
#define NB   1024   // batch
#define NT   60     // time steps
#define NC   10     // in channels
#define NDM  256    // d_model
#define NH   16     // heads
#define NDH  16     // per-head value dim
#define NA   13     // num attention queries
#define NM   208    // NA*NH
#define NMO  128    // MLP out

// weff6 row: 128 groups x 32 floats (128 B aligned); group g = d-pair (2g, 2g+1),
// slot dl*13+ak for dl in {0,1}; slots 26..31 pad. Row = 4096 floats.
#define WROW6 4096

// Workspace layout (floats)
#define OFF_WEFF  0
#define N_WEFF    (NH*14*WROW6)                // 917,504
#define OFF_BEFF  (OFF_WEFF + N_WEFF)
#define N_BEFF    (NM*NH*NA)                   // 43,264
#define OFF_VGT   (OFF_BEFF + N_BEFF)
#define N_VGT     (NB*NDM*64)                  // 16,777,216 (v transposed [b][d][64])
#define OFF_ATT   (OFF_VGT + N_VGT)
#define N_ATT     (NM*NB*NDH)                  // 3,407,872

#define LDS_FENCE() __asm__ __volatile__("s_waitcnt lgkmcnt(0)" ::: "memory")

// ---------------- K0: weff6[hk][mi][g][32], m = 13*hk+mi
__global__ void ltae_weff(const float* __restrict__ Q, const float* __restrict__ Wk,
                          const float* __restrict__ bk, float* __restrict__ weff6,
                          float* __restrict__ beff2) {
    int blk = blockIdx.x;            // hk*14 + mi
    int hk = blk / 14, mi = blk - hk*14;
    int m  = hk*13 + mi;
    int mc = m > 207 ? 207 : m;      // slot (15,13) provably never read
    int d = threadIdx.x;
    float q0 = Q[mc*4+0], q1 = Q[mc*4+1], q2 = Q[mc*4+2], q3 = Q[mc*4+3];
    int g = d >> 1, dl = d & 1;
    size_t base = (size_t)blk*WROW6 + g*32 + dl*13;
#pragma unroll
    for (int ak = 0; ak < NA; ++ak) {
        int e = (ak*16 + hk)*4;
        float w = q0*Wk[(size_t)(e+0)*NDM + d] + q1*Wk[(size_t)(e+1)*NDM + d]
                + q2*Wk[(size_t)(e+2)*NDM + d] + q3*Wk[(size_t)(e+3)*NDM + d];
        weff6[base + ak] = w;
    }
    if (dl == 1) {               // zero the 6 pad slots of this group
#pragma unroll
        for (int p = 26; p < 32; ++p) weff6[(size_t)blk*WROW6 + g*32 + p] = 0.f;
    }
    if (d < NA && m <= 207) {
        int e = (d*16 + hk)*4;
        beff2[(m*16 + hk)*NA + d] = q0*bk[e] + q1*bk[e+1] + q2*bk[e+2] + q3*bk[e+3];
    }
}

// ---------------- K1: conv 1x1 + GroupNorm -> vgT[b][d][64] (t-padded, coalesced)
#define VT_S 66
#define K1_LDS_BYTES ((NDM*VT_S + NT*NC)*4)

__launch_bounds__(1024, 8)
__global__ void ltae_convgn(const float* __restrict__ x, const float* __restrict__ Wc,
                            const float* __restrict__ bc, const float* __restrict__ gnw,
                            const float* __restrict__ gnb, float* __restrict__ vgT) {
    extern __shared__ float smem[];
    float* Vt = smem;
    float* xs = smem + NDM*VT_S;
    int b = blockIdx.x, tid = threadIdx.x;
    if (tid < NT*NC) xs[tid] = x[(size_t)b*NT*NC + tid];
    __syncthreads();
    {
        int d = tid >> 2, q = tid & 3;   // wave = 16 d = one GN group
        float wc[NC];
#pragma unroll
        for (int c = 0; c < NC; ++c) wc[c] = Wc[d*NC + c];
        float bcv = bc[d];
        float h[15];
        float s1 = 0.f, s2 = 0.f;
#pragma unroll
        for (int k = 0; k < 15; ++k) {
            int t = 15*q + k;
            float a = bcv;
#pragma unroll
            for (int c = 0; c < NC; ++c) a = fmaf(xs[t*NC + c], wc[c], a);
            h[k] = a; s1 += a; s2 += a*a;
        }
#pragma unroll
        for (int off = 1; off < 64; off <<= 1) {
            s1 += __shfl_xor(s1, off);
            s2 += __shfl_xor(s2, off);
        }
        float mean = s1 * (1.f/960.f);
        float var  = s2 * (1.f/960.f) - mean*mean;
        float rstd = rsqrtf(var + 1e-5f);
        float g = gnw[d], bb = gnb[d];
#pragma unroll
        for (int k = 0; k < 15; ++k)
            Vt[d*VT_S + 15*q + k] = (h[k]-mean)*rstd*g + bb;
    }
    __syncthreads();
    // float4 stores: 4x fewer store instructions than scalar
    float* vb = vgT + (size_t)b*NDM*64;
    for (int i = tid; i < NDM*16; i += 1024) {
        int d = i >> 4, t4 = (i & 15) << 2;
        float4 o;
        o.x = (t4+0 < NT) ? Vt[d*VT_S + t4+0] : 0.f;
        o.y = (t4+1 < NT) ? Vt[d*VT_S + t4+1] : 0.f;
        o.z = (t4+2 < NT) ? Vt[d*VT_S + t4+2] : 0.f;
        o.w = (t4+3 < NT) ? Vt[d*VT_S + t4+3] : 0.f;
        *(float4*)&vb[d*64 + t4] = o;
    }
}

// ---------------- K2: scrambled attention; wave = (1 b, 2 hk), 2-wave blocks.
// R6 diagnosis: HBM-latency-bound (200k cyc/wave = ~2700 cyc/gg-iter ~= 3x900cy
// serial miss chains; L2 thrashes at 8MB working set/XCD), and the 16-wg/CU HW
// cap blocked the TLP fix (1-wave blocks stuck at ~14 waves/CU).
// Fixes: (1) wave owns 1b x 2hk, not 2b x 1hk: v traffic per wave HALVES,
// arithmetic intensity per loaded byte DOUBLES (52 FMA per 512B group).
// (2) 4 groups per iter, 8 loads issued up-front: one latency window per
// 416 FMA-cycles, 8 loads deep. (3) 128-thread blocks: 16wg x 2 waves =
// 32 waves/CU possible. Weights stay direct uniform s_load operands
// (R1/R3 lesson: register arrays spill; occupancy is the binding resource).
#define BSTRIDE (NDM*64)
__launch_bounds__(128, 8)
__global__ void ltae_attn(const float* __restrict__ vgT, const float* __restrict__ weff6,
                          const float* __restrict__ beff2, float* __restrict__ attout) {
    __shared__ float wbuf[2*784];        // 6,272 B (per-wave scratch x2)
    int p = blockIdx.x;                  // 4096 = 8 xcd * 128 b * 4 blkpb
    int xcd = p & 7, idx = p >> 3;
    int b  = xcd * 128 + (idx >> 2);     // bijective: 8*128*4 = 4096
    int blkpb = idx & 3;
    int tid = threadIdx.x;
    int wid = tid >> 6, lane = tid & 63;
    int hkp = blkpb*2 + wid;             // wave's hk pair index, 0..7
    int hk0 = __builtin_amdgcn_readfirstlane(hkp*2);     // wave-uniform scalars
    int hk1 = hk0 + 1;
    int tk = lane;
    int mi0   = (13*b) >> 10;                            // wave-uniform
    int rstar = ((mi0+1) << 10) - 13*b;                  // pass B iff rstar < 13
    const float* __restrict__ wrow0 = weff6 + (size_t)(hk0*14 + mi0)*WROW6;
    const float* __restrict__ wrow1 = weff6 + (size_t)(hk1*14 + mi0)*WROW6;
    const float* __restrict__ vB    = vgT + (size_t)b*BSTRIDE + tk;
    float* myC = wbuf + wid*784;

    float acc[2][13];                    // [h2][ak], h2 = hk0/hk1
#pragma unroll
    for (int h2 = 0; h2 < 2; ++h2)
#pragma unroll
        for (int j = 0; j < 13; ++j) acc[h2][j] = 0.f;

    // ---- pass A: 128 d-pair groups, 4 per iteration; 8 v loads issued
    // up-front per iteration (one latency window per 416 FMA-cycles).
#pragma unroll 1
    for (int gq = 0; gq < 32; ++gq) {
        float v0 = vB[(8*gq+0)*64], v1 = vB[(8*gq+1)*64];
        float v2 = vB[(8*gq+2)*64], v3 = vB[(8*gq+3)*64];
        float v4 = vB[(8*gq+4)*64], v5 = vB[(8*gq+5)*64];
        float v6 = vB[(8*gq+6)*64], v7 = vB[(8*gq+7)*64];
#pragma unroll
        for (int gl = 0; gl < 4; ++gl) {
            const float* wg0 = wrow0 + (size_t)(4*gq+gl)*32;   // uniform s_load
            const float* wg1 = wrow1 + (size_t)(4*gq+gl)*32;
            float a0 = (gl==0)?v0:(gl==1)?v2:(gl==2)?v4:v6;
            float a1 = (gl==0)?v1:(gl==1)?v3:(gl==2)?v5:v7;
#pragma unroll
            for (int ak = 0; ak < 13; ++ak)
                acc[0][ak] = fmaf(a1, wg0[13+ak], fmaf(a0, wg0[ak], acc[0][ak]));
#pragma unroll
            for (int ak = 0; ak < 13; ++ak)
                acc[1][ak] = fmaf(a1, wg1[13+ak], fmaf(a0, wg1[ak], acc[1][ak]));
        }
    }

    // ---- pass B (rare, ~1% of b): rows r >= rstar use weight row mi0+1.
    // Recompute for both hk; save/restore the mi0-row prefix at t* boundary.
    if (rstar < 13) {
        int ustar = 60*rstar;
        int tstar = (ustar >= 1) ? (ustar/13) : -1;
        if (tk == tstar) {
#pragma unroll
            for (int j = 0; j < 13; ++j) { myC[j] = acc[0][j]; myC[13+j] = acc[1][j]; }
        }
        LDS_FENCE();
        if (tk >= tstar) {
#pragma unroll
            for (int h2 = 0; h2 < 2; ++h2)
#pragma unroll
                for (int j = 0; j < 13; ++j) acc[h2][j] = 0.f;
            const float* __restrict__ w20 = weff6 + (size_t)(hk0*14 + mi0 + 1)*WROW6;
            const float* __restrict__ w21 = weff6 + (size_t)(hk1*14 + mi0 + 1)*WROW6;
#pragma unroll 1
            for (int g = 0; g < 128; ++g) {
                const float* wg0 = w20 + (size_t)g*32;
                const float* wg1 = w21 + (size_t)g*32;
                float v0 = vB[(2*g)*64];
                float v1 = vB[(2*g+1)*64];
#pragma unroll
                for (int ak = 0; ak < 13; ++ak)
                    acc[0][ak] = fmaf(v1, wg0[13+ak], fmaf(v0, wg0[ak], acc[0][ak]));
#pragma unroll
                for (int ak = 0; ak < 13; ++ak)
                    acc[1][ak] = fmaf(v1, wg1[13+ak], fmaf(v0, wg1[ak], acc[1][ak]));
            }
        }
        if (tk == tstar) {
#pragma unroll
            for (int j = 0; j < 13; ++j)
                if (13*tk + j < ustar) { acc[0][j] = myC[j]; acc[1][j] = myC[13+j]; }
        }
        LDS_FENCE();
    }

    // ---- softmax + AV per hk; FULLY UNROLLED h2 (static acc indexing)
    int dh = lane >> 2, cc = lane & 3;
#pragma unroll
    for (int h2 = 0; h2 < 2; ++h2) {
        int hk = hk0 + h2;
        int hb13 = (hk*1024 + b)*13;
        if (tk < NT) {
#pragma unroll
            for (int j = 0; j < 13; ++j) myC[13*tk + j] = acc[h2][j];
        }
        LDS_FENCE();
        float vreg[15];
#pragma unroll
        for (int j = 0; j < 15; ++j)
            vreg[j] = vgT[((size_t)b*NDM + hk*16 + dh)*64 + cc + 4*j];
#pragma unroll 1
        for (int r = 0; r < 13; ++r) {
            int n = hb13 + r;
            int m = n >> 10;                         // exact variant for this row
            int brow = (m*16 + hk)*13;
            float logit = -1e30f;
            if (lane < NT) {
                int u  = r*60 + lane;
                int ak = u % 13;
                logit = (myC[u] + beff2[brow + ak]) * 0.5f;
            }
            float mx = logit;
#pragma unroll
            for (int off = 32; off; off >>= 1) mx = fmaxf(mx, __shfl_xor(mx, off));
            float e = (lane < NT) ? __expf(logit - mx) : 0.f;
            float s = e;
#pragma unroll
            for (int off = 32; off; off >>= 1) s += __shfl_xor(s, off);
            float attn = e / s;
            if (lane < NT) myC[r*60 + lane] = attn;  // same-wave in-order LDS
            LDS_FENCE();
            float a = 0.f;
#pragma unroll
            for (int j = 0; j < 15; ++j)
                a = fmaf(myC[r*60 + cc + 4*j], vreg[j], a);
            a += __shfl_xor(a, 1);
            a += __shfl_xor(a, 2);
            if (cc == 0) attout[(size_t)n*NDH + dh] = a;
        }
        LDS_FENCE();
    }
}

// ---------------- K3: MLP + BN(eval) + ReLU + GroupNorm(16,128); 16 rows/block,
// each thread computes 2 rows per W1-row load.
__launch_bounds__(1024)
__global__ void ltae_mlp(const float* __restrict__ attout, const float* __restrict__ W1,
                         const float* __restrict__ b1, const float* __restrict__ bnw,
                         const float* __restrict__ bnb, const float* __restrict__ bnrm,
                         const float* __restrict__ bnrv, const float* __restrict__ gow,
                         const float* __restrict__ gob, float* __restrict__ out) {
    __shared__ float f[16][NDM];
    int tid = threadIdx.x;
    int sl  = tid >> 7;          // 0..7
    int j   = tid & 127;
    int base = blockIdx.x << 4;  // 16 sids per block; sid = a2*1024 + b2
    for (int k = tid; k < 16*NDM; k += 1024) {
        int s = k >> 8, c = k & 255;
        int sid2 = base + s;
        int aa = sid2 >> 10, bb = sid2 & 1023;
        int h2 = c >> 4, dhh = c & 15;
        f[s][c] = attout[((size_t)((aa*16 + h2)*1024 + bb))*NDH + dhh];
    }
    __syncthreads();
    const float* fr0 = f[sl];
    const float* fr1 = f[sl + 8];
    const float* w   = &W1[(size_t)j*NDM];
    float bj = b1[j];
    float acc0 = bj, acc1 = bj;
    for (int c = 0; c < NDM; c += 4) {
        float4 wv = *(const float4*)&w[c];
        acc0 += wv.x*fr0[c] + wv.y*fr0[c+1] + wv.z*fr0[c+2] + wv.w*fr0[c+3];
        acc1 += wv.x*fr1[c] + wv.y*fr1[c+1] + wv.z*fr1[c+2] + wv.w*fr1[c+3];
    }
    float rs = rsqrtf(bnrv[j] + 1e-5f);
    float sc = rs * bnw[j];
    float sh = bnb[j] - bnrm[j]*sc;
    float y0 = fmaxf(acc0*sc + sh, 0.f);
    float y1 = fmaxf(acc1*sc + sh, 0.f);
    float a1 = y0, b1s = y0*y0, a2 = y1, b2s = y1*y1;
#pragma unroll
    for (int off = 1; off < 8; off <<= 1) {
        a1  += __shfl_xor(a1, off);
        b1s += __shfl_xor(b1s, off);
        a2  += __shfl_xor(a2, off);
        b2s += __shfl_xor(b2s, off);
    }
    float gw = gow[j], gb = gob[j];
    {
        float mean = a1 * 0.125f;
        float var  = b1s * 0.125f - mean*mean;
        float o = (y0 - mean) * rsqrtf(var + 1e-5f) * gw + gb;
        int sid = base + sl, aa = sid >> 10, bb = sid & 1023;
        out[((size_t)bb*NA + aa)*NMO + j] = o;
    }
    {
        float mean = a2 * 0.125f;
        float var  = b2s * 0.125f - mean*mean;
        float o = (y1 - mean) * rsqrtf(var + 1e-5f) * gw + gb;
        int sid = base + sl + 8, aa = sid >> 10, bb = sid & 1023;
        out[((size_t)bb*NA + aa)*NMO + j] = o;
    }
}

extern "C" void kernel_launch(void* const* d_in, const int* in_sizes, int n_in,
                              void* d_out, int out_size, void* d_ws, size_t ws_size,
                              hipStream_t stream) {
    const float* x    = (const float*)d_in[0];
    const float* Wc   = (const float*)d_in[1];
    const float* bc   = (const float*)d_in[2];
    const float* gnw  = (const float*)d_in[3];
    const float* gnb  = (const float*)d_in[4];
    const float* Q    = (const float*)d_in[5];
    const float* Wk   = (const float*)d_in[6];
    const float* bk   = (const float*)d_in[7];
    const float* W1   = (const float*)d_in[8];
    const float* b1   = (const float*)d_in[9];
    const float* bnw  = (const float*)d_in[10];
    const float* bnb  = (const float*)d_in[11];
    const float* bnrm = (const float*)d_in[12];
    const float* bnrv = (const float*)d_in[13];
    const float* gow  = (const float*)d_in[14];
    const float* gob  = (const float*)d_in[15];

    float* ws     = (float*)d_ws;
    float* weff6  = ws + OFF_WEFF;
    float* beff2  = ws + OFF_BEFF;
    float* vgT    = ws + OFF_VGT;
    float* attout = ws + OFF_ATT;
    float* outp   = (float*)d_out;

    hipLaunchKernelGGL(ltae_weff, dim3(NH*14), dim3(256), 0, stream, Q, Wk, bk, weff6, beff2);
    hipFuncSetAttribute((const void*)ltae_convgn,
                        hipFuncAttributeMaxDynamicSharedMemorySize, K1_LDS_BYTES);
    hipLaunchKernelGGL(ltae_convgn, dim3(NB), dim3(1024), K1_LDS_BYTES, stream,
                       x, Wc, bc, gnw, gnb, vgT);
    hipLaunchKernelGGL(ltae_attn, dim3(4096), dim3(128), 0, stream,
                       vgT, weff6, beff2, attout);
    hipLaunchKernelGGL(ltae_mlp, dim3(NA*NB/16), dim3(1024), 0, stream,
                       attout, W1, b1, bnw, bnb, bnrm, bnrv, gow, gob, outp);
}